// Round 9
// baseline (396.974 us; speedup 1.0000x reference)
//
#include <hip/hip_runtime.h>
#include <hip/hip_fp16.h>

// Problem constants
#define B_     8
#define NCAM   5
#define J_     15
#define H_     128
#define W_     240
#define NB     128000             // bins = 80*80*20
#define HW_    (H_ * W_)          // 30720
// Overlapping row-pair f16 image: dword[y][x] = (f16 v(y,x), f16 v(y+1,x)),
// y in 0..H-2. Any clamped 2x2 window = dwords (yc,xc),(yc,xc+1): ONE
// ds_read2_b32 per sample, all 8B useful.
#define OV_ROWS (H_ - 1)          // 127
#define OV_DW   (OV_ROWS * W_)    // 30480 dwords
#define OV_G4   (OV_DW / 4)       // 7620 uint4 groups
// R9: unlock the VGPR budget. At TPB=1024 the budget is a hard 64 (R2-R8).
// VGPR pool: waves/EU halves at 64/128/256 regs -> 2 waves/EU = 256 regs.
// TPB=512 (8 waves, LDS-limited to 1 block/CU anyway) + launch_bounds(512,2)
// requests exactly that. Then NCHUNK=4 (best staging amortization, R1) +
// 64 items/thread + 8-item fence levels (R6 mechanism) = depth-8 pipeline,
// peak live ~130 << 256. Same LDS/stage instr totals as R1; latency hidden
// 8-deep instead of ~3.
#define TPB    512
#define NCHUNK 4                  // 480 blocks = 2 rounds of 256 CUs
#define BPB    (NB / NCHUNK)      // 32000 bins per block
#define ITEMS  64                 // 62 full + item62 partial(tid<256) + item63 void
#define NBJ    (B_ * J_)          // 120
#define NBLK   (NBJ * NCHUNK)     // 480

typedef __fp16 fp16x2 __attribute__((ext_vector_type(2)));

__device__ __forceinline__ unsigned int pkrtz(float lo, float hi) {
    fp16x2 h = __builtin_amdgcn_cvt_pkrtz(lo, hi);  // v_cvt_pkrtz_f16_f32
    return __builtin_bit_cast(unsigned int, h);
}

// f32 dot of two f16 pairs: v_dot2_f32_f16 (f32 accumulate).
__device__ __forceinline__ float fdot2(unsigned int d, unsigned int w, float c) {
#if __has_builtin(__builtin_amdgcn_fdot2)
    return __builtin_amdgcn_fdot2(__builtin_bit_cast(fp16x2, d),
                                  __builtin_bit_cast(fp16x2, w), c, false);
#else
    __half2 p = __hmul2(__builtin_bit_cast(__half2, d),
                        __builtin_bit_cast(__half2, w));
    return c + __low2float(p) + __high2float(p);
#endif
}

// Bilinear weights, padding_mode='zeros' validity folded into clamped 2x2
// window (validated R1-R8). Camera-mean 1/5 folded into weights.
// addr16 = yc*W + xc (max 30478, fits u16);
// w0pk=(0.2*a0*b0, 0.2*a0*b1) for col xc (pair over rows yc,yc+1),
// w1pk likewise for col xc+1 — matches overlap row-pair LDS dwords.
__device__ __forceinline__ void bilinear_rec(float gx, float gy,
                                             unsigned int& addr,
                                             unsigned int& w0pk,
                                             unsigned int& w1pk) {
    const float ix = (gx + 1.0f) * (0.5f * (W_ - 1));
    const float iy = (gy + 1.0f) * (0.5f * (H_ - 1));
    const float x0f = floorf(ix);
    const float y0f = floorf(iy);
    const float wx1 = ix - x0f, wx0 = 1.0f - wx1;
    const float wy1 = iy - y0f, wy0 = 1.0f - wy1;
    const int x0 = (int)x0f;
    const int y0 = (int)y0f;
    const int xc = min(max(x0, 0), W_ - 2);
    const int yc = min(max(y0, 0), H_ - 2);
    const float vx0 = (x0 >= 0  && x0 <= W_ - 1) ? wx0 : 0.0f;
    const float vx1 = (x0 >= -1 && x0 <= W_ - 2) ? wx1 : 0.0f;
    const float vy0 = (y0 >= 0  && y0 <= H_ - 1) ? wy0 : 0.0f;
    const float vy1 = (y0 >= -1 && y0 <= H_ - 2) ? wy1 : 0.0f;
    const bool xhi = (x0 == W_ - 1);
    const bool xlo = (x0 == -1);
    const bool yhi = (y0 == H_ - 1);
    const bool ylo = (y0 == -1);
    const float a0 = (xhi ? 0.0f : vx0) + (xlo ? vx1 : 0.0f);
    const float a1 = (xhi ? vx0 : 0.0f) + (xlo ? 0.0f : vx1);
    const float b0 = (yhi ? 0.0f : vy0) + (ylo ? vy1 : 0.0f);
    const float b1 = (yhi ? vy0 : 0.0f) + (ylo ? 0.0f : vy1);
    addr = (unsigned int)(yc * W_ + xc);
    w0pk = pkrtz(0.2f * (a0 * b0), 0.2f * (a0 * b1));
    w1pk = pkrtz(0.2f * (a1 * b0), 0.2f * (a1 * b1));
}

__global__ __launch_bounds__(256) void weights_kernel(
    const float* __restrict__ sgrid,          // [NCAM, NB, 2]
    unsigned short* __restrict__ addr16,      // [NCAM*NB]
    uint2* __restrict__ wpk)                  // [NCAM*NB]
{
    const int i = blockIdx.x * 256 + threadIdx.x;
    if (i >= NCAM * NB) return;
    const float2 g = ((const float2*)sgrid)[i];
    unsigned int a, w0, w1;
    bilinear_rec(g.x, g.y, a, w0, w1);
    addr16[i] = (unsigned short)a;
    wpk[i] = make_uint2(w0, w1);
}

// Stage f32 HxW image as overlapping row-pair f16 dwords (121.9 KB).
__device__ __forceinline__ void stage_overlap(const float* __restrict__ img,
                                              unsigned int* s_img, int tid) {
    const float4* __restrict__ src4 = (const float4*)img;  // 60 groups per row
    uint4* dst = (uint4*)s_img;
    for (int gi = tid; gi < OV_G4; gi += TPB) {
        const int y  = gi / 60;
        const int xg = gi - y * 60;
        const float4 t = src4[y * 60 + xg];        // row y
        const float4 b = src4[y * 60 + 60 + xg];   // row y+1
        uint4 d;
        d.x = pkrtz(t.x, b.x);
        d.y = pkrtz(t.y, b.y);
        d.z = pkrtz(t.z, b.z);
        d.w = pkrtz(t.w, b.w);
        dst[gi] = d;
    }
}

// ---- named-scalar macros (no arrays; all indices literal) ----
#define LOADI(IT) \
    const unsigned int a##IT = ap[(IT) * TPB + tid]; \
    const uint2        w##IT = wp[(IT) * TPB + tid];
// clamped + zero-select (items 62, 63): never OOB, garbage*0 == 0
#define LOADI_C(IT) \
    const int rc##IT = min((IT) * TPB + tid, BPB - 1); \
    const unsigned int a##IT = ap[rc##IT]; \
    const uint2        wt##IT = wp[rc##IT]; \
    const uint2        w##IT = ((IT) * TPB + tid < bpb) ? wt##IT \
                                                        : make_uint2(0u, 0u);
#define DSI(IT) \
    const unsigned int p##IT = s_img[a##IT]; \
    const unsigned int q##IT = s_img[a##IT + 1u];
#define DOTI(IT) \
    acc##IT = fdot2(q##IT, w##IT.y, fdot2(p##IT, w##IT.x, acc##IT));
#define SDI(IT) DSI(IT) DOTI(IT)
#define OUTI(IT) \
    if ((IT) * TPB + tid < BPB) \
        o[(IT) * TPB + tid] = fminf(fmaxf(acc##IT, 0.0f), 1.0f);

// Static LDS 121.9 KB -> 1 block/CU = 8 waves = 2 waves/EU.
// launch_bounds(512, 2): min 2 waves/EU -> 256-VGPR budget (the unlock).
__global__ __launch_bounds__(TPB, 2) void project_kernel(
    const float* __restrict__ hm,             // [B, NCAM, J, H, W]
    const unsigned short* __restrict__ addr16,
    const uint2* __restrict__ wpk,
    float* __restrict__ out,                  // [B, J, NB]
    int bpb)                                  // == BPB; runtime-opaque fence
{
    __shared__ unsigned int s_img[OV_DW];     // STATIC: 121920 B
    const int tid   = threadIdx.x;
    // bj-major mapping: same-bj blocks at bids bj+120k; 120%8==0 -> same XCD,
    // so all 4 chunks of a (b,j) share one XCD's L2 for the staged images.
    const int bj    = blockIdx.x % NBJ;
    const int chunk = blockIdx.x / NBJ;
    const int b     = bj / J_;
    const int j     = bj % J_;
    const int bin0  = chunk * BPB;

    float acc0  = 0.f, acc1  = 0.f, acc2  = 0.f, acc3  = 0.f,
          acc4  = 0.f, acc5  = 0.f, acc6  = 0.f, acc7  = 0.f;
    float acc8  = 0.f, acc9  = 0.f, acc10 = 0.f, acc11 = 0.f,
          acc12 = 0.f, acc13 = 0.f, acc14 = 0.f, acc15 = 0.f;
    float acc16 = 0.f, acc17 = 0.f, acc18 = 0.f, acc19 = 0.f,
          acc20 = 0.f, acc21 = 0.f, acc22 = 0.f, acc23 = 0.f;
    float acc24 = 0.f, acc25 = 0.f, acc26 = 0.f, acc27 = 0.f,
          acc28 = 0.f, acc29 = 0.f, acc30 = 0.f, acc31 = 0.f;
    float acc32 = 0.f, acc33 = 0.f, acc34 = 0.f, acc35 = 0.f,
          acc36 = 0.f, acc37 = 0.f, acc38 = 0.f, acc39 = 0.f;
    float acc40 = 0.f, acc41 = 0.f, acc42 = 0.f, acc43 = 0.f,
          acc44 = 0.f, acc45 = 0.f, acc46 = 0.f, acc47 = 0.f;
    float acc48 = 0.f, acc49 = 0.f, acc50 = 0.f, acc51 = 0.f,
          acc52 = 0.f, acc53 = 0.f, acc54 = 0.f, acc55 = 0.f;
    float acc56 = 0.f, acc57 = 0.f, acc58 = 0.f, acc59 = 0.f,
          acc60 = 0.f, acc61 = 0.f, acc62 = 0.f, acc63 = 0.f;

    for (int n = 0; n < NCAM; ++n) {
        const unsigned short* __restrict__ ap = addr16 + n * NB + bin0;
        const uint2* __restrict__ wp = wpk + n * NB + bin0;
        // Level-0 weight loads before staging: L2/L3 latency hides under it.
        LOADI(0) LOADI(1) LOADI(2) LOADI(3)
        LOADI(4) LOADI(5) LOADI(6) LOADI(7)
        __syncthreads();          // prev camera's sampling done
        stage_overlap(hm + (((size_t)b * NCAM + n) * J_ + j) * HW_, s_img, tid);
        __syncthreads();
        // 8 fence levels (opaque bpb guards, all true at runtime): level k
        // issues level k+1's 8 weight loads, then ds+dot of its own 8 items.
        // Peak live ~130 regs << 256 budget.
        if (tid < bpb) {                                       // L0
            LOADI(8) LOADI(9) LOADI(10) LOADI(11)
            LOADI(12) LOADI(13) LOADI(14) LOADI(15)
            SDI(0) SDI(1) SDI(2) SDI(3) SDI(4) SDI(5) SDI(6) SDI(7)
            if (1 * TPB + tid < bpb) {                         // L1
                LOADI(16) LOADI(17) LOADI(18) LOADI(19)
                LOADI(20) LOADI(21) LOADI(22) LOADI(23)
                SDI(8) SDI(9) SDI(10) SDI(11)
                SDI(12) SDI(13) SDI(14) SDI(15)
                if (2 * TPB + tid < bpb) {                     // L2
                    LOADI(24) LOADI(25) LOADI(26) LOADI(27)
                    LOADI(28) LOADI(29) LOADI(30) LOADI(31)
                    SDI(16) SDI(17) SDI(18) SDI(19)
                    SDI(20) SDI(21) SDI(22) SDI(23)
                    if (3 * TPB + tid < bpb) {                 // L3
                        LOADI(32) LOADI(33) LOADI(34) LOADI(35)
                        LOADI(36) LOADI(37) LOADI(38) LOADI(39)
                        SDI(24) SDI(25) SDI(26) SDI(27)
                        SDI(28) SDI(29) SDI(30) SDI(31)
                        if (4 * TPB + tid < bpb) {             // L4
                            LOADI(40) LOADI(41) LOADI(42) LOADI(43)
                            LOADI(44) LOADI(45) LOADI(46) LOADI(47)
                            SDI(32) SDI(33) SDI(34) SDI(35)
                            SDI(36) SDI(37) SDI(38) SDI(39)
                            if (5 * TPB + tid < bpb) {         // L5
                                LOADI(48) LOADI(49) LOADI(50) LOADI(51)
                                LOADI(52) LOADI(53) LOADI(54) LOADI(55)
                                SDI(40) SDI(41) SDI(42) SDI(43)
                                SDI(44) SDI(45) SDI(46) SDI(47)
                                if (6 * TPB + tid < bpb) {     // L6
                                    LOADI(56) LOADI(57) LOADI(58) LOADI(59)
                                    LOADI(60) LOADI(61) LOADI_C(62) LOADI_C(63)
                                    SDI(48) SDI(49) SDI(50) SDI(51)
                                    SDI(52) SDI(53) SDI(54) SDI(55)
                                    if (7 * TPB + tid < bpb) { // L7
                                        SDI(56) SDI(57) SDI(58) SDI(59)
                                        SDI(60) SDI(61) SDI(62) SDI(63)
                                    }
                                }
                            }
                        }
                    }
                }
            }
        }
    }

    float* __restrict__ o = out + (size_t)bj * NB + bin0;
    OUTI(0)  OUTI(1)  OUTI(2)  OUTI(3)  OUTI(4)  OUTI(5)  OUTI(6)  OUTI(7)
    OUTI(8)  OUTI(9)  OUTI(10) OUTI(11) OUTI(12) OUTI(13) OUTI(14) OUTI(15)
    OUTI(16) OUTI(17) OUTI(18) OUTI(19) OUTI(20) OUTI(21) OUTI(22) OUTI(23)
    OUTI(24) OUTI(25) OUTI(26) OUTI(27) OUTI(28) OUTI(29) OUTI(30) OUTI(31)
    OUTI(32) OUTI(33) OUTI(34) OUTI(35) OUTI(36) OUTI(37) OUTI(38) OUTI(39)
    OUTI(40) OUTI(41) OUTI(42) OUTI(43) OUTI(44) OUTI(45) OUTI(46) OUTI(47)
    OUTI(48) OUTI(49) OUTI(50) OUTI(51) OUTI(52) OUTI(53) OUTI(54) OUTI(55)
    OUTI(56) OUTI(57) OUTI(58) OUTI(59) OUTI(60) OUTI(61) OUTI(62) OUTI(63)
}

// Fallback (tiny ws): R1-style f32-LDS kernel, inline weights. 600 blocks.
#define FBT       1024
#define FB_SMEM   (HW_ * 4)
#define FB_NCHUNK 5
#define FB_BPB    (NB / FB_NCHUNK)   // 25600
#define FB_ITEMS  (FB_BPB / FBT)     // 25
__global__ __launch_bounds__(FBT) void project_fallback(
    const float* __restrict__ hm,
    const float* __restrict__ sgrid,
    float* __restrict__ out)
{
    extern __shared__ float s_f32[];
    const int tid   = threadIdx.x;
    const int bj    = blockIdx.x % NBJ;
    const int chunk = blockIdx.x / NBJ;
    const int b     = bj / J_;
    const int j     = bj % J_;
    const int bin0  = chunk * FB_BPB;

    float acc[FB_ITEMS];
#pragma unroll
    for (int it = 0; it < FB_ITEMS; ++it) acc[it] = 0.0f;

    for (int n = 0; n < NCAM; ++n) {
        __syncthreads();
        const float4* __restrict__ src =
            (const float4*)(hm + (((size_t)b * NCAM + n) * J_ + j) * HW_);
        float4* dst = (float4*)s_f32;
        for (int i = tid; i < HW_ / 4; i += FBT) dst[i] = src[i];
        __syncthreads();
        const float2* __restrict__ g2 = (const float2*)sgrid + n * NB + bin0;
#pragma unroll
        for (int it = 0; it < FB_ITEMS; ++it) {
            const float2 g = g2[it * FBT + tid];
            const float ix = (g.x + 1.0f) * (0.5f * (W_ - 1));
            const float iy = (g.y + 1.0f) * (0.5f * (H_ - 1));
            const float x0f = floorf(ix), y0f = floorf(iy);
            const float wx1 = ix - x0f, wx0 = 1.0f - wx1;
            const float wy1 = iy - y0f, wy0 = 1.0f - wy1;
            const int x0 = (int)x0f, y0 = (int)y0f;
            const int xc = min(max(x0, 0), W_ - 2);
            const int yc = min(max(y0, 0), H_ - 2);
            const float vx0 = (x0 >= 0  && x0 <= W_ - 1) ? wx0 : 0.0f;
            const float vx1 = (x0 >= -1 && x0 <= W_ - 2) ? wx1 : 0.0f;
            const float vy0 = (y0 >= 0  && y0 <= H_ - 1) ? wy0 : 0.0f;
            const float vy1 = (y0 >= -1 && y0 <= H_ - 2) ? wy1 : 0.0f;
            const bool xhi = (x0 == W_ - 1), xlo = (x0 == -1);
            const bool yhi = (y0 == H_ - 1), ylo = (y0 == -1);
            const float a0 = (xhi ? 0.0f : vx0) + (xlo ? vx1 : 0.0f);
            const float a1 = (xhi ? vx0 : 0.0f) + (xlo ? 0.0f : vx1);
            const float b0 = (yhi ? 0.0f : vy0) + (ylo ? vy1 : 0.0f);
            const float b1 = (yhi ? vy0 : 0.0f) + (ylo ? 0.0f : vy1);
            const float* r0 = s_f32 + (yc * W_ + xc);
            acc[it] += b0 * (a0 * r0[0] + a1 * r0[1])
                     + b1 * (a0 * r0[W_] + a1 * r0[W_ + 1]);
        }
    }
    float* __restrict__ o = out + (size_t)bj * NB + bin0;
#pragma unroll
    for (int it = 0; it < FB_ITEMS; ++it)
        o[it * FBT + tid] = fminf(fmaxf(acc[it] * 0.2f, 0.0f), 1.0f);
}

extern "C" void kernel_launch(void* const* d_in, const int* in_sizes, int n_in,
                              void* d_out, int out_size, void* d_ws, size_t ws_size,
                              hipStream_t stream) {
    const float* hm = (const float*)d_in[0];   // [8,5,15,128,240] f32
    const float* sg = (const float*)d_in[1];   // [5,128000,2] f32
    float* out = (float*)d_out;                // [8,15,128000] f32

    (void)hipFuncSetAttribute((const void*)project_fallback,
                              hipFuncAttributeMaxDynamicSharedMemorySize, FB_SMEM);

    const size_t addr_bytes = (size_t)NCAM * NB * sizeof(unsigned short); // 1.28 MB
    const size_t wpk_bytes  = (size_t)NCAM * NB * sizeof(uint2);          // 5.12 MB
    if (ws_size >= addr_bytes + wpk_bytes) {
        unsigned short* addr16 = (unsigned short*)d_ws;
        uint2* wpk = (uint2*)((char*)d_ws + addr_bytes);
        weights_kernel<<<(NCAM * NB + 255) / 256, 256, 0, stream>>>(sg, addr16, wpk);
        project_kernel<<<NBLK, TPB, 0, stream>>>(hm, addr16, wpk, out, BPB);
    } else {
        project_fallback<<<NBJ * FB_NCHUNK, FBT, FB_SMEM, stream>>>(hm, sg, out);
    }
}

// Round 10
// 304.213 us; speedup vs baseline: 1.3049x; 1.3049x over previous
//
#include <hip/hip_runtime.h>
#include <hip/hip_fp16.h>

// Problem constants
#define B_     8
#define NCAM   5
#define J_     15
#define H_     128
#define W_     240
#define NB     128000             // bins = 80*80*20
#define HW_    (H_ * W_)          // 30720
// R10: R7's proven structure (X-pair f16 double-buffer, overlapped staging,
// opaque fence levels -- 122us, zero spill) moved to TPB=512.
// Budget map (measured): TPB=1024 -> 64 VGPRs (R2-R8); TPB=512 -> 128 (R9).
// At 512 threads: ITEMS=32, 8 levels x 4 items, peak live ~68 << 128.
// Trade: TLP 4->2 waves/EU for 2x per-level ILP + 2x per-thread work.
// X-pair layout: dword[y][xp] = (f16 v(y,2xp), f16 v(y,2xp+1)), 61.4 KB per
// image, two buffers fit LDS; stage cam n+1 interleaved with sampling cam n.
#define XP_DW   15360             // dwords per image buffer
#define XP_PAD  15368             // +8 dwords pad, keeps buf1 16B-aligned
#define XP_G4   (XP_DW / 4)       // 3840 uint4 stage units
#define TPB    512
#define NCHUNK 8                  // 960 blocks, 1/CU resident
#define BPB    (NB / NCHUNK)      // 16000 bins per block
#define ITEMS  32                 // 31 full + item31 partial (tid < 128)
#define NBJ    (B_ * J_)          // 120
#define NBLK   (NBJ * NCHUNK)     // 960

typedef __fp16 fp16x2 __attribute__((ext_vector_type(2)));

__device__ __forceinline__ unsigned int pkrtz(float lo, float hi) {
    fp16x2 h = __builtin_amdgcn_cvt_pkrtz(lo, hi);  // v_cvt_pkrtz_f16_f32
    return __builtin_bit_cast(unsigned int, h);
}

// f32 dot of two f16 pairs: v_dot2_f32_f16 (f32 accumulate).
__device__ __forceinline__ float fdot2(unsigned int d, unsigned int w, float c) {
#if __has_builtin(__builtin_amdgcn_fdot2)
    return __builtin_amdgcn_fdot2(__builtin_bit_cast(fp16x2, d),
                                  __builtin_bit_cast(fp16x2, w), c, false);
#else
    __half2 p = __hmul2(__builtin_bit_cast(__half2, d),
                        __builtin_bit_cast(__half2, w));
    return c + __low2float(p) + __high2float(p);
#endif
}

// Bilinear weights, padding_mode='zeros' validity folded into clamped 2x2
// window (validated R0-R9; X-pair packing validated R7). 1/5 folded in.
// addr16 = (yc*120 + (xc>>1)) | ((xc&1) << 14)   (max 15239 < 2^14)
// w0pk = (0.2*a0*b0, 0.2*a1*b0)  -- row yc, cols (xc, xc+1)
// w1pk = (0.2*a0*b1, 0.2*a1*b1)  -- row yc+1
__device__ __forceinline__ void bilinear_rec(float gx, float gy,
                                             unsigned int& addr,
                                             unsigned int& w0pk,
                                             unsigned int& w1pk) {
    const float ix = (gx + 1.0f) * (0.5f * (W_ - 1));
    const float iy = (gy + 1.0f) * (0.5f * (H_ - 1));
    const float x0f = floorf(ix);
    const float y0f = floorf(iy);
    const float wx1 = ix - x0f, wx0 = 1.0f - wx1;
    const float wy1 = iy - y0f, wy0 = 1.0f - wy1;
    const int x0 = (int)x0f;
    const int y0 = (int)y0f;
    const int xc = min(max(x0, 0), W_ - 2);
    const int yc = min(max(y0, 0), H_ - 2);
    const float vx0 = (x0 >= 0  && x0 <= W_ - 1) ? wx0 : 0.0f;
    const float vx1 = (x0 >= -1 && x0 <= W_ - 2) ? wx1 : 0.0f;
    const float vy0 = (y0 >= 0  && y0 <= H_ - 1) ? wy0 : 0.0f;
    const float vy1 = (y0 >= -1 && y0 <= H_ - 2) ? wy1 : 0.0f;
    const bool xhi = (x0 == W_ - 1);
    const bool xlo = (x0 == -1);
    const bool yhi = (y0 == H_ - 1);
    const bool ylo = (y0 == -1);
    const float a0 = (xhi ? 0.0f : vx0) + (xlo ? vx1 : 0.0f);
    const float a1 = (xhi ? vx0 : 0.0f) + (xlo ? 0.0f : vx1);
    const float b0 = (yhi ? 0.0f : vy0) + (ylo ? vy1 : 0.0f);
    const float b1 = (yhi ? vy0 : 0.0f) + (ylo ? 0.0f : vy1);
    const int xp = xc >> 1;
    const int p  = xc & 1;
    addr = (unsigned int)(yc * 120 + xp) | ((unsigned int)p << 14);
    w0pk = pkrtz(0.2f * (a0 * b0), 0.2f * (a1 * b0));
    w1pk = pkrtz(0.2f * (a0 * b1), 0.2f * (a1 * b1));
}

__global__ __launch_bounds__(256) void weights_kernel(
    const float* __restrict__ sgrid,          // [NCAM, NB, 2]
    unsigned short* __restrict__ addr16,      // [NCAM*NB]
    uint2* __restrict__ wpk)                  // [NCAM*NB]
{
    const int i = blockIdx.x * 256 + threadIdx.x;
    if (i >= NCAM * NB) return;
    const float2 g = ((const float2*)sgrid)[i];
    unsigned int a, w0, w1;
    bilinear_rec(g.x, g.y, a, w0, w1);
    addr16[i] = (unsigned short)a;
    wpk[i] = make_uint2(w0, w1);
}

// ---- named-scalar macros (no arrays; all indices literal) ----
#define LOADI(IT) \
    const unsigned int a##IT = ap[(IT) * TPB + tid]; \
    const uint2        w##IT = wp[(IT) * TPB + tid];
// tail item: clamped in-bounds load + zero weights (garbage*0 == 0)
#define LOADI_T(IT) \
    const int rt##IT = min((IT) * TPB + tid, BPB - 1); \
    const unsigned int a##IT = ap[rt##IT]; \
    const uint2        wt##IT = wp[rt##IT]; \
    const uint2        w##IT = tail_ok ? wt##IT : make_uint2(0u, 0u);
// X-pair LDS fetch: rows yc,yc+1 at xp (ds_read2 0/120); odd-xc lanes also
// read xp+1 (divergent, ~half lanes active).
#define DSI(IT) \
    const unsigned int pa##IT = a##IT & 0x3FFFu; \
    const unsigned int d00_##IT = cbuf[pa##IT]; \
    const unsigned int d10_##IT = cbuf[pa##IT + 120u]; \
    unsigned int d01_##IT = 0u, d11_##IT = 0u; \
    if (a##IT >> 14) { d01_##IT = cbuf[pa##IT + 1u]; \
                       d11_##IT = cbuf[pa##IT + 121u]; }
// splice (xc, xc+1) pair per row: even sel = passthrough d00/d10.
#define DOTI(IT) { \
    const unsigned int sel##IT = 0x03020100u + (a##IT >> 14) * 0x02020202u; \
    const unsigned int r0##IT = __builtin_amdgcn_perm(d01_##IT, d00_##IT, sel##IT); \
    const unsigned int r1##IT = __builtin_amdgcn_perm(d11_##IT, d10_##IT, sel##IT); \
    acc##IT = fdot2(r1##IT, w##IT.y, fdot2(r0##IT, w##IT.x, acc##IT)); }
// one staging unit: 2 float4 -> 4 x-pair dwords -> ds_write_b128 into nxt buf
// 3840 units / 512 threads = 7.5 -> units 0..6 full, unit 7 half (tid<256).
#define STAGE_UNIT(K) \
    if (stage_on && ((K) * TPB + tid < XP_G4)) { \
        const int gi##K = (K) * TPB + tid; \
        const int row##K = gi##K / 30; \
        const int xg##K = gi##K - row##K * 30; \
        const float4 t0##K = src4[row##K * 60 + 2 * xg##K]; \
        const float4 t1##K = src4[row##K * 60 + 2 * xg##K + 1]; \
        nxt4[row##K * 30 + xg##K] = \
            make_uint4(pkrtz(t0##K.x, t0##K.y), pkrtz(t0##K.z, t0##K.w), \
                       pkrtz(t1##K.x, t1##K.y), pkrtz(t1##K.z, t1##K.w)); \
    }
#define OUTI(IT) \
    if ((IT) * TPB + tid < BPB) \
        o[(IT) * TPB + tid] = fminf(fmaxf(acc##IT, 0.0f), 1.0f);

// Static LDS 122.9 KB -> 1 block/CU = 8 waves = 2 waves/EU.
// launch_bounds(512,2): measured 128-VGPR budget (R9). Peak live ~68.
__global__ __launch_bounds__(TPB, 2) void project_kernel(
    const float* __restrict__ hm,             // [B, NCAM, J, H, W]
    const unsigned short* __restrict__ addr16,
    const uint2* __restrict__ wpk,
    float* __restrict__ out,                  // [B, J, NB]
    int bpb)                                  // == BPB; runtime-opaque fence
{
    __shared__ __align__(16) unsigned int s_img[2][XP_PAD];  // 122944 B
    const int tid   = threadIdx.x;
    // bj-major mapping: same-bj blocks at bids bj+120k; 120%8==0 -> same XCD,
    // so all 8 chunks of a (b,j) share one XCD's L2 for the staged images.
    const int bj    = blockIdx.x % NBJ;
    const int chunk = blockIdx.x / NBJ;
    const int b     = bj / J_;
    const int j     = bj % J_;
    const int bin0  = chunk * BPB;
    // item 31: r = 31*512+tid < 16000  <=>  tid < 128 (wave-uniform x2)
    const bool tail_ok = (tid < BPB - (ITEMS - 1) * TPB);

    float acc0  = 0.f, acc1  = 0.f, acc2  = 0.f, acc3  = 0.f,
          acc4  = 0.f, acc5  = 0.f, acc6  = 0.f, acc7  = 0.f;
    float acc8  = 0.f, acc9  = 0.f, acc10 = 0.f, acc11 = 0.f,
          acc12 = 0.f, acc13 = 0.f, acc14 = 0.f, acc15 = 0.f;
    float acc16 = 0.f, acc17 = 0.f, acc18 = 0.f, acc19 = 0.f,
          acc20 = 0.f, acc21 = 0.f, acc22 = 0.f, acc23 = 0.f;
    float acc24 = 0.f, acc25 = 0.f, acc26 = 0.f, acc27 = 0.f,
          acc28 = 0.f, acc29 = 0.f, acc30 = 0.f, acc31 = 0.f;

    // Prologue: stage camera 0 into buf0 (the only serial staging).
    {
        const float4* __restrict__ s0 =
            (const float4*)(hm + (((size_t)b * NCAM + 0) * J_ + j) * HW_);
        uint4* __restrict__ d0 = (uint4*)(&s_img[0][0]);
        for (int gi = tid; gi < XP_G4; gi += TPB) {
            const int row = gi / 30;
            const int xg = gi - row * 30;
            const float4 t0 = s0[row * 60 + 2 * xg];
            const float4 t1 = s0[row * 60 + 2 * xg + 1];
            d0[row * 30 + xg] =
                make_uint4(pkrtz(t0.x, t0.y), pkrtz(t0.z, t0.w),
                           pkrtz(t1.x, t1.y), pkrtz(t1.z, t1.w));
        }
    }
    __syncthreads();

    for (int n = 0; n < NCAM; ++n) {
        const unsigned short* __restrict__ ap = addr16 + n * NB + bin0;
        const uint2* __restrict__ wp = wpk + n * NB + bin0;
        const unsigned int* __restrict__ cbuf = &s_img[n & 1][0];
        uint4* __restrict__ nxt4 = (uint4*)(&s_img[(n + 1) & 1][0]);
        const bool stage_on = (n < NCAM - 1);
        const int np = stage_on ? n + 1 : n;
        const float4* __restrict__ src4 =
            (const float4*)(hm + (((size_t)b * NCAM + np) * J_ + j) * HW_);

        LOADI(0) LOADI(1) LOADI(2) LOADI(3)
        // 8 fence levels (opaque bpb guards, all true at runtime). Level k:
        // issue level k+1's weight loads | 1 stage unit | ds+dot 4 items.
        if (tid < bpb) {                                       // L0
            LOADI(4) LOADI(5) LOADI(6) LOADI(7)
            STAGE_UNIT(0)
            DSI(0) DSI(1) DOTI(0) DOTI(1)
            DSI(2) DSI(3) DOTI(2) DOTI(3)
            if (1 * TPB + tid < bpb) {                         // L1
                LOADI(8) LOADI(9) LOADI(10) LOADI(11)
                STAGE_UNIT(1)
                DSI(4) DSI(5) DOTI(4) DOTI(5)
                DSI(6) DSI(7) DOTI(6) DOTI(7)
                if (2 * TPB + tid < bpb) {                     // L2
                    LOADI(12) LOADI(13) LOADI(14) LOADI(15)
                    STAGE_UNIT(2)
                    DSI(8) DSI(9) DOTI(8) DOTI(9)
                    DSI(10) DSI(11) DOTI(10) DOTI(11)
                    if (3 * TPB + tid < bpb) {                 // L3
                        LOADI(16) LOADI(17) LOADI(18) LOADI(19)
                        STAGE_UNIT(3)
                        DSI(12) DSI(13) DOTI(12) DOTI(13)
                        DSI(14) DSI(15) DOTI(14) DOTI(15)
                        if (4 * TPB + tid < bpb) {             // L4
                            LOADI(20) LOADI(21) LOADI(22) LOADI(23)
                            STAGE_UNIT(4)
                            DSI(16) DSI(17) DOTI(16) DOTI(17)
                            DSI(18) DSI(19) DOTI(18) DOTI(19)
                            if (5 * TPB + tid < bpb) {         // L5
                                LOADI(24) LOADI(25) LOADI(26) LOADI(27)
                                STAGE_UNIT(5)
                                DSI(20) DSI(21) DOTI(20) DOTI(21)
                                DSI(22) DSI(23) DOTI(22) DOTI(23)
                                if (6 * TPB + tid < bpb) {     // L6
                                    LOADI(28) LOADI(29) LOADI(30) LOADI_T(31)
                                    STAGE_UNIT(6)
                                    DSI(24) DSI(25) DOTI(24) DOTI(25)
                                    DSI(26) DSI(27) DOTI(26) DOTI(27)
                                    if (7 * TPB + tid < bpb) { // L7
                                        STAGE_UNIT(7)
                                        DSI(28) DSI(29) DOTI(28) DOTI(29)
                                        DSI(30) DSI(31) DOTI(30) DOTI(31)
                                    }
                                }
                            }
                        }
                    }
                }
            }
        }
        __syncthreads();   // cam n reads done; cam n+1 buffer complete
    }

    float* __restrict__ o = out + (size_t)bj * NB + bin0;
    OUTI(0)  OUTI(1)  OUTI(2)  OUTI(3)  OUTI(4)  OUTI(5)  OUTI(6)  OUTI(7)
    OUTI(8)  OUTI(9)  OUTI(10) OUTI(11) OUTI(12) OUTI(13) OUTI(14) OUTI(15)
    OUTI(16) OUTI(17) OUTI(18) OUTI(19) OUTI(20) OUTI(21) OUTI(22) OUTI(23)
    OUTI(24) OUTI(25) OUTI(26) OUTI(27) OUTI(28) OUTI(29) OUTI(30) OUTI(31)
}

// Fallback (tiny ws): R1-style f32-LDS kernel, inline weights. 600 blocks.
#define FBT       1024
#define FB_SMEM   (HW_ * 4)
#define FB_NCHUNK 5
#define FB_BPB    (NB / FB_NCHUNK)   // 25600
#define FB_ITEMS  (FB_BPB / FBT)     // 25
__global__ __launch_bounds__(FBT) void project_fallback(
    const float* __restrict__ hm,
    const float* __restrict__ sgrid,
    float* __restrict__ out)
{
    extern __shared__ float s_f32[];
    const int tid   = threadIdx.x;
    const int bj    = blockIdx.x % NBJ;
    const int chunk = blockIdx.x / NBJ;
    const int b     = bj / J_;
    const int j     = bj % J_;
    const int bin0  = chunk * FB_BPB;

    float acc[FB_ITEMS];
#pragma unroll
    for (int it = 0; it < FB_ITEMS; ++it) acc[it] = 0.0f;

    for (int n = 0; n < NCAM; ++n) {
        __syncthreads();
        const float4* __restrict__ src =
            (const float4*)(hm + (((size_t)b * NCAM + n) * J_ + j) * HW_);
        float4* dst = (float4*)s_f32;
        for (int i = tid; i < HW_ / 4; i += FBT) dst[i] = src[i];
        __syncthreads();
        const float2* __restrict__ g2 = (const float2*)sgrid + n * NB + bin0;
#pragma unroll
        for (int it = 0; it < FB_ITEMS; ++it) {
            const float2 g = g2[it * FBT + tid];
            const float ix = (g.x + 1.0f) * (0.5f * (W_ - 1));
            const float iy = (g.y + 1.0f) * (0.5f * (H_ - 1));
            const float x0f = floorf(ix), y0f = floorf(iy);
            const float wx1 = ix - x0f, wx0 = 1.0f - wx1;
            const float wy1 = iy - y0f, wy0 = 1.0f - wy1;
            const int x0 = (int)x0f, y0 = (int)y0f;
            const int xc = min(max(x0, 0), W_ - 2);
            const int yc = min(max(y0, 0), H_ - 2);
            const float vx0 = (x0 >= 0  && x0 <= W_ - 1) ? wx0 : 0.0f;
            const float vx1 = (x0 >= -1 && x0 <= W_ - 2) ? wx1 : 0.0f;
            const float vy0 = (y0 >= 0  && y0 <= H_ - 1) ? wy0 : 0.0f;
            const float vy1 = (y0 >= -1 && y0 <= H_ - 2) ? wy1 : 0.0f;
            const bool xhi = (x0 == W_ - 1), xlo = (x0 == -1);
            const bool yhi = (y0 == H_ - 1), ylo = (y0 == -1);
            const float a0 = (xhi ? 0.0f : vx0) + (xlo ? vx1 : 0.0f);
            const float a1 = (xhi ? vx0 : 0.0f) + (xlo ? 0.0f : vx1);
            const float b0 = (yhi ? 0.0f : vy0) + (ylo ? vy1 : 0.0f);
            const float b1 = (yhi ? vy0 : 0.0f) + (ylo ? 0.0f : vy1);
            const float* r0 = s_f32 + (yc * W_ + xc);
            acc[it] += b0 * (a0 * r0[0] + a1 * r0[1])
                     + b1 * (a0 * r0[W_] + a1 * r0[W_ + 1]);
        }
    }
    float* __restrict__ o = out + (size_t)bj * NB + bin0;
#pragma unroll
    for (int it = 0; it < FB_ITEMS; ++it)
        o[it * FBT + tid] = fminf(fmaxf(acc[it] * 0.2f, 0.0f), 1.0f);
}

extern "C" void kernel_launch(void* const* d_in, const int* in_sizes, int n_in,
                              void* d_out, int out_size, void* d_ws, size_t ws_size,
                              hipStream_t stream) {
    const float* hm = (const float*)d_in[0];   // [8,5,15,128,240] f32
    const float* sg = (const float*)d_in[1];   // [5,128000,2] f32
    float* out = (float*)d_out;                // [8,15,128000] f32

    (void)hipFuncSetAttribute((const void*)project_fallback,
                              hipFuncAttributeMaxDynamicSharedMemorySize, FB_SMEM);

    const size_t addr_bytes = (size_t)NCAM * NB * sizeof(unsigned short); // 1.28 MB
    const size_t wpk_bytes  = (size_t)NCAM * NB * sizeof(uint2);          // 5.12 MB
    if (ws_size >= addr_bytes + wpk_bytes) {
        unsigned short* addr16 = (unsigned short*)d_ws;
        uint2* wpk = (uint2*)((char*)d_ws + addr_bytes);
        weights_kernel<<<(NCAM * NB + 255) / 256, 256, 0, stream>>>(sg, addr16, wpk);
        project_kernel<<<NBLK, TPB, 0, stream>>>(hm, addr16, wpk, out, BPB);
    } else {
        project_fallback<<<NBJ * FB_NCHUNK, FBT, FB_SMEM, stream>>>(hm, sg, out);
    }
}

// Round 11
// 212.487 us; speedup vs baseline: 1.8682x; 1.4317x over previous
//
#include <hip/hip_runtime.h>
#include <hip/hip_fp16.h>

// Problem constants
#define B_     8
#define NCAM   5
#define J_     15
#define H_     128
#define W_     240
#define NB     128000             // bins = 80*80*20
#define HW_    (H_ * W_)          // 30720
// FINAL (R11 = verified R7, session best: 211.4us total / 122us kernel).
// X-pair f16 layout: dword[y][xp] = (f16 v(y,2xp), f16 v(y,2xp+1)),
// y in 0..127, xp in 0..119. 15360 dwords = 61.4 KB per image:
//  - staging reads each f32 ONCE
//  - TWO buffers fit LDS (122.9 KB) -> double-buffer: stage cam n+1
//    interleaved with sampling cam n; ONE barrier per camera.
// Session law (R1-R10): VGPR budget is HARD 64 @TPB=1024 / 128 @TPB=512;
// only small fence levels (<=2 items in flight) stay clean (R1/R6/R7 at
// 52-56 VGPRs). Deeper ILP (R9/R10) and bigger accumulator sets (R2-R5)
// all spill ~300+us. Three clean structures plateau at 119-134us ->
// latency/mixed-bound (LDS ~44%, VMEM ~30%, VALU ~30% of wall, none
// saturated). This config is the measured optimum.
#define XP_DW   15360             // dwords per image buffer
#define XP_PAD  15368             // +8 dwords pad, keeps buf1 16B-aligned
#define XP_G4   (XP_DW / 4)       // 3840 uint4 stage units
#define TPB    1024
#define NCHUNK 8                  // 960 blocks
#define BPB    (NB / NCHUNK)      // 16000 bins per block
#define ITEMS  16                 // item 15 partial (tid < 640)
#define NBJ    (B_ * J_)          // 120
#define NBLK   (NBJ * NCHUNK)     // 960

typedef __fp16 fp16x2 __attribute__((ext_vector_type(2)));

__device__ __forceinline__ unsigned int pkrtz(float lo, float hi) {
    fp16x2 h = __builtin_amdgcn_cvt_pkrtz(lo, hi);  // v_cvt_pkrtz_f16_f32
    return __builtin_bit_cast(unsigned int, h);
}

// f32 dot of two f16 pairs: v_dot2_f32_f16 (f32 accumulate).
__device__ __forceinline__ float fdot2(unsigned int d, unsigned int w, float c) {
#if __has_builtin(__builtin_amdgcn_fdot2)
    return __builtin_amdgcn_fdot2(__builtin_bit_cast(fp16x2, d),
                                  __builtin_bit_cast(fp16x2, w), c, false);
#else
    __half2 p = __hmul2(__builtin_bit_cast(__half2, d),
                        __builtin_bit_cast(__half2, w));
    return c + __low2float(p) + __high2float(p);
#endif
}

// Bilinear weights, padding_mode='zeros' validity folded into clamped 2x2
// window (validated R0-R10). Camera-mean 1/5 folded in.
// addr16 = (yc*120 + (xc>>1)) | ((xc&1) << 14)   (max 15239 < 2^14, fits)
// w0pk = (0.2*a0*b0, 0.2*a1*b0)  -- row yc, cols (xc, xc+1)
// w1pk = (0.2*a0*b1, 0.2*a1*b1)  -- row yc+1
__device__ __forceinline__ void bilinear_rec(float gx, float gy,
                                             unsigned int& addr,
                                             unsigned int& w0pk,
                                             unsigned int& w1pk) {
    const float ix = (gx + 1.0f) * (0.5f * (W_ - 1));
    const float iy = (gy + 1.0f) * (0.5f * (H_ - 1));
    const float x0f = floorf(ix);
    const float y0f = floorf(iy);
    const float wx1 = ix - x0f, wx0 = 1.0f - wx1;
    const float wy1 = iy - y0f, wy0 = 1.0f - wy1;
    const int x0 = (int)x0f;
    const int y0 = (int)y0f;
    const int xc = min(max(x0, 0), W_ - 2);
    const int yc = min(max(y0, 0), H_ - 2);
    const float vx0 = (x0 >= 0  && x0 <= W_ - 1) ? wx0 : 0.0f;
    const float vx1 = (x0 >= -1 && x0 <= W_ - 2) ? wx1 : 0.0f;
    const float vy0 = (y0 >= 0  && y0 <= H_ - 1) ? wy0 : 0.0f;
    const float vy1 = (y0 >= -1 && y0 <= H_ - 2) ? wy1 : 0.0f;
    const bool xhi = (x0 == W_ - 1);
    const bool xlo = (x0 == -1);
    const bool yhi = (y0 == H_ - 1);
    const bool ylo = (y0 == -1);
    const float a0 = (xhi ? 0.0f : vx0) + (xlo ? vx1 : 0.0f);
    const float a1 = (xhi ? vx0 : 0.0f) + (xlo ? 0.0f : vx1);
    const float b0 = (yhi ? 0.0f : vy0) + (ylo ? vy1 : 0.0f);
    const float b1 = (yhi ? vy0 : 0.0f) + (ylo ? 0.0f : vy1);
    const int xp = xc >> 1;
    const int p  = xc & 1;
    addr = (unsigned int)(yc * 120 + xp) | ((unsigned int)p << 14);
    w0pk = pkrtz(0.2f * (a0 * b0), 0.2f * (a1 * b0));
    w1pk = pkrtz(0.2f * (a0 * b1), 0.2f * (a1 * b1));
}

__global__ __launch_bounds__(256) void weights_kernel(
    const float* __restrict__ sgrid,          // [NCAM, NB, 2]
    unsigned short* __restrict__ addr16,      // [NCAM*NB]
    uint2* __restrict__ wpk)                  // [NCAM*NB]
{
    const int i = blockIdx.x * 256 + threadIdx.x;
    if (i >= NCAM * NB) return;
    const float2 g = ((const float2*)sgrid)[i];
    unsigned int a, w0, w1;
    bilinear_rec(g.x, g.y, a, w0, w1);
    addr16[i] = (unsigned short)a;
    wpk[i] = make_uint2(w0, w1);
}

// ---- named-scalar macros (no arrays; all indices literal) ----
#define LOADI(IT) \
    const unsigned int a##IT = ap[(IT) * TPB + tid]; \
    const uint2        w##IT = wp[(IT) * TPB + tid];
// tail item: clamped in-bounds load + zero weights (garbage*0 == 0)
#define LOADI_T(IT) \
    const int rt##IT = min((IT) * TPB + tid, BPB - 1); \
    const unsigned int a##IT = ap[rt##IT]; \
    const uint2        wt##IT = wp[rt##IT]; \
    const uint2        w##IT = tail_ok ? wt##IT : make_uint2(0u, 0u);
// X-pair LDS fetch: always rows yc,yc+1 at xp (one ds_read2 0/120);
// odd-xc lanes also need xp+1 (divergent branch ~half the lanes).
#define DSI(IT) \
    const unsigned int pa##IT = a##IT & 0x3FFFu; \
    const unsigned int d00_##IT = cbuf[pa##IT]; \
    const unsigned int d10_##IT = cbuf[pa##IT + 120u]; \
    unsigned int d01_##IT = 0u, d11_##IT = 0u; \
    if (a##IT >> 14) { d01_##IT = cbuf[pa##IT + 1u]; \
                       d11_##IT = cbuf[pa##IT + 121u]; }
// splice (xc, xc+1) pair per row: even sel = passthrough d00/d10.
#define DOTI(IT) { \
    const unsigned int sel##IT = 0x03020100u + (a##IT >> 14) * 0x02020202u; \
    const unsigned int r0##IT = __builtin_amdgcn_perm(d01_##IT, d00_##IT, sel##IT); \
    const unsigned int r1##IT = __builtin_amdgcn_perm(d11_##IT, d10_##IT, sel##IT); \
    acc##IT = fdot2(r1##IT, w##IT.y, fdot2(r0##IT, w##IT.x, acc##IT)); }
// one staging unit: 2 float4 -> 4 x-pair dwords -> ds_write_b128 into nxt buf
#define STAGE_UNIT(K) \
    if (stage_on && ((K) * TPB + tid < XP_G4)) { \
        const int gi##K = (K) * TPB + tid; \
        const int row##K = gi##K / 30; \
        const int xg##K = gi##K - row##K * 30; \
        const float4 t0##K = src4[row##K * 60 + 2 * xg##K]; \
        const float4 t1##K = src4[row##K * 60 + 2 * xg##K + 1]; \
        nxt4[row##K * 30 + xg##K] = \
            make_uint4(pkrtz(t0##K.x, t0##K.y), pkrtz(t0##K.z, t0##K.w), \
                       pkrtz(t1##K.x, t1##K.y), pkrtz(t1##K.z, t1##K.w)); \
    }
#define OUTI(IT) \
    if ((IT) * TPB + tid < BPB) \
        o[(IT) * TPB + tid] = fminf(fmaxf(acc##IT, 0.0f), 1.0f);

// Static LDS 122.9 KB -> 1 block/CU, 16 waves. Opaque-bpb fence levels
// keep peak live ~52 regs < the hard 64-VGPR budget (measured clean).
__global__ __launch_bounds__(TPB, 4) void project_kernel(
    const float* __restrict__ hm,             // [B, NCAM, J, H, W]
    const unsigned short* __restrict__ addr16,
    const uint2* __restrict__ wpk,
    float* __restrict__ out,                  // [B, J, NB]
    int bpb)                                  // == BPB; runtime-opaque fence
{
    __shared__ __align__(16) unsigned int s_img[2][XP_PAD];  // 122944 B
    const int tid   = threadIdx.x;
    // bj-major mapping: same-bj blocks at bids bj+120k; 120%8==0 -> same XCD,
    // so all 8 chunks of a (b,j) share one XCD's L2 for the staged images.
    const int bj    = blockIdx.x % NBJ;
    const int chunk = blockIdx.x / NBJ;
    const int b     = bj / J_;
    const int j     = bj % J_;
    const int bin0  = chunk * BPB;
    const bool tail_ok = (tid < BPB - (ITEMS - 1) * TPB);   // tid < 640

    float acc0 = 0.f, acc1 = 0.f, acc2 = 0.f, acc3 = 0.f;
    float acc4 = 0.f, acc5 = 0.f, acc6 = 0.f, acc7 = 0.f;
    float acc8 = 0.f, acc9 = 0.f, acc10 = 0.f, acc11 = 0.f;
    float acc12 = 0.f, acc13 = 0.f, acc14 = 0.f, acc15 = 0.f;

    // Prologue: stage camera 0 into buf0 (serial; only place that's serial).
    {
        const float4* __restrict__ s0 =
            (const float4*)(hm + (((size_t)b * NCAM + 0) * J_ + j) * HW_);
        uint4* __restrict__ d0 = (uint4*)(&s_img[0][0]);
        for (int gi = tid; gi < XP_G4; gi += TPB) {
            const int row = gi / 30;
            const int xg = gi - row * 30;
            const float4 t0 = s0[row * 60 + 2 * xg];
            const float4 t1 = s0[row * 60 + 2 * xg + 1];
            d0[row * 30 + xg] =
                make_uint4(pkrtz(t0.x, t0.y), pkrtz(t0.z, t0.w),
                           pkrtz(t1.x, t1.y), pkrtz(t1.z, t1.w));
        }
    }
    __syncthreads();

    for (int n = 0; n < NCAM; ++n) {
        const unsigned short* __restrict__ ap = addr16 + n * NB + bin0;
        const uint2* __restrict__ wp = wpk + n * NB + bin0;
        const unsigned int* __restrict__ cbuf = &s_img[n & 1][0];
        uint4* __restrict__ nxt4 = (uint4*)(&s_img[(n + 1) & 1][0]);
        const bool stage_on = (n < NCAM - 1);
        const int np = stage_on ? n + 1 : n;
        const float4* __restrict__ src4 =
            (const float4*)(hm + (((size_t)b * NCAM + np) * J_ + j) * HW_);

        LOADI(0) LOADI(1) LOADI(2) LOADI(3)
        // Fence levels (all guards true at runtime; bpb is opaque):
        // sample cam n from cbuf || stage cam n+1 into nxt4, no serial phase.
        if (tid < bpb) {                                       // L0
            LOADI(4) LOADI(5) LOADI(6) LOADI(7)
            STAGE_UNIT(0)
            if (1 * TPB + tid < bpb) {                         // L1
                DSI(0) DSI(1) DOTI(0) DOTI(1)
                DSI(2) DSI(3) DOTI(2) DOTI(3)
                if (2 * TPB + tid < bpb) {                     // L2
                    LOADI(8) LOADI(9) LOADI(10) LOADI(11)
                    STAGE_UNIT(1)
                    if (3 * TPB + tid < bpb) {                 // L3
                        DSI(4) DSI(5) DOTI(4) DOTI(5)
                        DSI(6) DSI(7) DOTI(6) DOTI(7)
                        if (4 * TPB + tid < bpb) {             // L4
                            LOADI(12) LOADI(13) LOADI(14) LOADI_T(15)
                            STAGE_UNIT(2)
                            if (5 * TPB + tid < bpb) {         // L5
                                DSI(8) DSI(9) DOTI(8) DOTI(9)
                                DSI(10) DSI(11) DOTI(10) DOTI(11)
                                if (6 * TPB + tid < bpb) {     // L6
                                    STAGE_UNIT(3)
                                    if (7 * TPB + tid < bpb) { // L7
                                        DSI(12) DSI(13) DOTI(12) DOTI(13)
                                        DSI(14) DSI(15) DOTI(14) DOTI(15)
                                    }
                                }
                            }
                        }
                    }
                }
            }
        }
        __syncthreads();   // cam n reads done; cam n+1 buffer complete
    }

    float* __restrict__ o = out + (size_t)bj * NB + bin0;
    OUTI(0) OUTI(1) OUTI(2) OUTI(3) OUTI(4) OUTI(5) OUTI(6) OUTI(7)
    OUTI(8) OUTI(9) OUTI(10) OUTI(11) OUTI(12) OUTI(13) OUTI(14) OUTI(15)
}

// Fallback (tiny ws): R1-style f32-LDS kernel, inline weights. 600 blocks.
#define FB_SMEM   (HW_ * 4)
#define FB_NCHUNK 5
#define FB_BPB    (NB / FB_NCHUNK)   // 25600
#define FB_ITEMS  (FB_BPB / TPB)     // 25
__global__ __launch_bounds__(TPB) void project_fallback(
    const float* __restrict__ hm,
    const float* __restrict__ sgrid,
    float* __restrict__ out)
{
    extern __shared__ float s_f32[];
    const int tid   = threadIdx.x;
    const int bj    = blockIdx.x % NBJ;
    const int chunk = blockIdx.x / NBJ;
    const int b     = bj / J_;
    const int j     = bj % J_;
    const int bin0  = chunk * FB_BPB;

    float acc[FB_ITEMS];
#pragma unroll
    for (int it = 0; it < FB_ITEMS; ++it) acc[it] = 0.0f;

    for (int n = 0; n < NCAM; ++n) {
        __syncthreads();
        const float4* __restrict__ src =
            (const float4*)(hm + (((size_t)b * NCAM + n) * J_ + j) * HW_);
        float4* dst = (float4*)s_f32;
        for (int i = tid; i < HW_ / 4; i += TPB) dst[i] = src[i];
        __syncthreads();
        const float2* __restrict__ g2 = (const float2*)sgrid + n * NB + bin0;
#pragma unroll
        for (int it = 0; it < FB_ITEMS; ++it) {
            const float2 g = g2[it * TPB + tid];
            const float ix = (g.x + 1.0f) * (0.5f * (W_ - 1));
            const float iy = (g.y + 1.0f) * (0.5f * (H_ - 1));
            const float x0f = floorf(ix), y0f = floorf(iy);
            const float wx1 = ix - x0f, wx0 = 1.0f - wx1;
            const float wy1 = iy - y0f, wy0 = 1.0f - wy1;
            const int x0 = (int)x0f, y0 = (int)y0f;
            const int xc = min(max(x0, 0), W_ - 2);
            const int yc = min(max(y0, 0), H_ - 2);
            const float vx0 = (x0 >= 0  && x0 <= W_ - 1) ? wx0 : 0.0f;
            const float vx1 = (x0 >= -1 && x0 <= W_ - 2) ? wx1 : 0.0f;
            const float vy0 = (y0 >= 0  && y0 <= H_ - 1) ? wy0 : 0.0f;
            const float vy1 = (y0 >= -1 && y0 <= H_ - 2) ? wy1 : 0.0f;
            const bool xhi = (x0 == W_ - 1), xlo = (x0 == -1);
            const bool yhi = (y0 == H_ - 1), ylo = (y0 == -1);
            const float a0 = (xhi ? 0.0f : vx0) + (xlo ? vx1 : 0.0f);
            const float a1 = (xhi ? vx0 : 0.0f) + (xlo ? 0.0f : vx1);
            const float b0 = (yhi ? 0.0f : vy0) + (ylo ? vy1 : 0.0f);
            const float b1 = (yhi ? vy0 : 0.0f) + (ylo ? 0.0f : vy1);
            const float* r0 = s_f32 + (yc * W_ + xc);
            acc[it] += b0 * (a0 * r0[0] + a1 * r0[1])
                     + b1 * (a0 * r0[W_] + a1 * r0[W_ + 1]);
        }
    }
    float* __restrict__ o = out + (size_t)bj * NB + bin0;
#pragma unroll
    for (int it = 0; it < FB_ITEMS; ++it)
        o[it * TPB + tid] = fminf(fmaxf(acc[it] * 0.2f, 0.0f), 1.0f);
}

extern "C" void kernel_launch(void* const* d_in, const int* in_sizes, int n_in,
                              void* d_out, int out_size, void* d_ws, size_t ws_size,
                              hipStream_t stream) {
    const float* hm = (const float*)d_in[0];   // [8,5,15,128,240] f32
    const float* sg = (const float*)d_in[1];   // [5,128000,2] f32
    float* out = (float*)d_out;                // [8,15,128000] f32

    (void)hipFuncSetAttribute((const void*)project_fallback,
                              hipFuncAttributeMaxDynamicSharedMemorySize, FB_SMEM);

    const size_t addr_bytes = (size_t)NCAM * NB * sizeof(unsigned short); // 1.28 MB
    const size_t wpk_bytes  = (size_t)NCAM * NB * sizeof(uint2);          // 5.12 MB
    if (ws_size >= addr_bytes + wpk_bytes) {
        unsigned short* addr16 = (unsigned short*)d_ws;
        uint2* wpk = (uint2*)((char*)d_ws + addr_bytes);
        weights_kernel<<<(NCAM * NB + 255) / 256, 256, 0, stream>>>(sg, addr16, wpk);
        project_kernel<<<NBLK, TPB, 0, stream>>>(hm, addr16, wpk, out, BPB);
    } else {
        project_fallback<<<NBJ * FB_NCHUNK, TPB, FB_SMEM, stream>>>(hm, sg, out);
    }
}